// Round 1
// baseline (491.595 us; speedup 1.0000x reference)
//
#include <hip/hip_runtime.h>

#define RC 130816   // 511*256
#define MT 512      // matT m-stride (511 zero-padded)

// bf16 weight cache layout (ushort offsets)
#define B16_FH   196608   // after 768*256 iou rows
#define B16_W1   262144   // 256*256 (W_attnh[:, :256])

__device__ __forceinline__ float rcpf(float x){ return __builtin_amdgcn_rcpf(x); }
__device__ __forceinline__ float sigmf(float x){ return rcpf(1.f + __expf(-x)); }
__device__ __forceinline__ float tanhfast(float x){
  return 1.f - 2.f*rcpf(1.f + __expf(2.f*x));
}

// ---- bf16-as-integer helpers ----
__device__ __forceinline__ float bfl(unsigned x){ return __uint_as_float(x << 16); }
__device__ __forceinline__ float bfh(unsigned x){ return __uint_as_float(x & 0xFFFF0000u); }
__device__ __forceinline__ unsigned bpack(float a, float b){
  unsigned ua = __float_as_uint(a), ub = __float_as_uint(b);
  return ((ua + 0x7FFFu + ((ua>>16)&1u)) >> 16)
       | ((ub + 0x7FFFu + ((ub>>16)&1u)) & 0xFFFF0000u);
}
__device__ __forceinline__ float dot8b(uint4 w, const float4* s4){
  float4 s0 = s4[0], s1 = s4[1];
  return bfl(w.x)*s0.x + bfh(w.x)*s0.y + bfl(w.y)*s0.z + bfh(w.y)*s0.w
       + bfl(w.z)*s1.x + bfh(w.z)*s1.y + bfl(w.w)*s1.z + bfh(w.w)*s1.w;
}

// ---------------------------------------------------------------------------
// Pack W_iouh / W_fh / W1 (=W_attnh[:,:256]) to bf16.
// ---------------------------------------------------------------------------
__global__ void __launch_bounds__(256) k_pack(
    const float* __restrict__ W_iouh, const float* __restrict__ W_fh,
    const float* __restrict__ W_attnh, unsigned* __restrict__ W16u)
{
  int g0 = blockIdx.x*blockDim.x + threadIdx.x, gs = gridDim.x*blockDim.x;
  for (int k = g0; k < 98304; k += gs){
    int i = 2*k; W16u[k] = bpack(W_iouh[i], W_iouh[i+1]);
  }
  for (int k = g0; k < 32768; k += gs){
    int i = 2*k; W16u[98304 + k] = bpack(W_fh[i], W_fh[i+1]);
  }
  for (int k = g0; k < 32768; k += gs){
    int i = 2*k; int t = i>>8, e = i&255;
    const float* r = W_attnh + (size_t)t*512;
    W16u[131072 + k] = bpack(r[e], r[e+1]);
  }
}

// ---------------------------------------------------------------------------
// Init: 256 blocks x 768 threads; block = (pass p, 2 rows).
// ---------------------------------------------------------------------------
__global__ void __launch_bounds__(768) k_init(
    const int* __restrict__ l_idx, const int* __restrict__ r_idx,
    const float* __restrict__ emb, const float* __restrict__ W_ioux,
    const float* __restrict__ b_ioux, const float* __restrict__ b_iouh,
    float* __restrict__ cmatA, float* __restrict__ matA,
    float* __restrict__ cmatB, float* __restrict__ matB)
{
  int b = blockIdx.x, tid = threadIdx.x;
  int p = b >> 7, n0 = (b & 127) * 2;
  __shared__ __align__(16) float xs[2*304];
  __shared__ float sg[2*768];
  for (int j = tid; j < 600; j += 768){
    int rr = j/300, d = j - rr*300;
    int row = p ? r_idx[n0+rr] : l_idx[n0+rr];
    xs[rr*304 + d] = emb[(size_t)row*300 + d];
  }
  __syncthreads();
  const float4* w = (const float4*)(W_ioux + (size_t)tid*300);
  float a0 = 0.f, a1 = 0.f;
  #pragma unroll 5
  for (int k = 0; k < 75; ++k){
    float4 wv = w[k];
    const float* x0 = xs + 4*k;
    const float* x1 = xs + 304 + 4*k;
    a0 += wv.x*x0[0] + wv.y*x0[1] + wv.z*x0[2] + wv.w*x0[3];
    a1 += wv.x*x1[0] + wv.y*x1[1] + wv.z*x1[2] + wv.w*x1[3];
  }
  float bb = b_ioux[tid] + b_iouh[tid];
  sg[tid] = a0 + bb;
  sg[768 + tid] = a1 + bb;
  __syncthreads();
  if (tid < 512){
    int rr = tid >> 8, t = tid & 255;
    const float* g = sg + rr*768;
    float c = sigmf(g[t]) * tanhfast(g[512+t]);
    float h = sigmf(g[256+t]) * tanhfast(c);
    (p ? cmatB : cmatA)[(size_t)(n0+rr)*256 + t] = c;
    (p ? matB  : matA )[(size_t)(n0+rr)*256 + t] = h;
  }
}

// ---------------------------------------------------------------------------
// A/B tree level, column-split S=4, row-batched R. 512 threads.
// blocks = (2*Nc/R)*4 : bid -> slice s (0..3), group (pass, R rows).
// Roles: 8 = gate{i,o,u,f} x d-half; LDS-combine partials.
// ---------------------------------------------------------------------------
template<int R>
__global__ void __launch_bounds__(512) k_levelAB(
    const unsigned short* __restrict__ W16, const float* __restrict__ b_iouh,
    const float* __restrict__ b_fh,
    int Nc, int offPrev, int offCur,
    float* __restrict__ cmatA, float* __restrict__ matA,
    float* __restrict__ cmatB, float* __restrict__ matB)
{
  int bid = blockIdx.x, tid = threadIdx.x;
  int s = bid & 3, g2 = bid >> 2;
  int groups = Nc / R;
  int p = (g2 >= groups) ? 1 : 0;
  int n0 = (g2 - p*groups) * R;
  float* cmat = p ? cmatB : cmatA;
  float* hmat = p ? matB  : matA;

  __shared__ __align__(16) float hs0[R][256], hs1[R][256], hss[R][256];
  __shared__ float sP[10][R][64];

  for (int it = tid; it < R*2*256; it += 512){
    int j = it & 255, ch = (it>>8)&1, r = it>>9;
    float v = hmat[(size_t)(offPrev + 2*(n0+r) + ch)*256 + j];
    if (ch) hs1[r][j] = v; else hs0[r][j] = v;
  }
  __syncthreads();
  for (int it = tid; it < R*256; it += 512){
    int j = it & 255, r = it>>8;
    hss[r][j] = hs0[r][j] + hs1[r][j];
  }
  __syncthreads();

  {
    int role = tid >> 6, cl = tid & 63;
    int gate = role & 3, dh = role >> 2;
    int col = s*64 + cl;
    if (gate < 3){
      const unsigned short* wrow = W16 + (size_t)(col + gate*256)*256;
      const uint4* w4 = (const uint4*)(wrow + dh*128);
      float acc[R];
      #pragma unroll
      for (int r = 0; r < R; ++r) acc[r] = 0.f;
      #pragma unroll 4
      for (int k = 0; k < 16; ++k){
        uint4 w = w4[k];
        #pragma unroll
        for (int r = 0; r < R; ++r)
          acc[r] += dot8b(w, (const float4*)(&hss[r][dh*128 + k*8]));
      }
      #pragma unroll
      for (int r = 0; r < R; ++r) sP[gate*2+dh][r][cl] = acc[r];
    } else {
      const uint4* w4 = (const uint4*)(W16 + B16_FH + (size_t)col*256 + dh*128);
      float a0[R], a1[R];
      #pragma unroll
      for (int r = 0; r < R; ++r){ a0[r] = 0.f; a1[r] = 0.f; }
      #pragma unroll 4
      for (int k = 0; k < 16; ++k){
        uint4 w = w4[k];
        #pragma unroll
        for (int r = 0; r < R; ++r){
          a0[r] += dot8b(w, (const float4*)(&hs0[r][dh*128 + k*8]));
          a1[r] += dot8b(w, (const float4*)(&hs1[r][dh*128 + k*8]));
        }
      }
      #pragma unroll
      for (int r = 0; r < R; ++r){ sP[6+dh][r][cl] = a0[r]; sP[8+dh][r][cl] = a1[r]; }
    }
  }
  __syncthreads();
  if (tid < 64*R){
    int r = tid >> 6, cl = tid & 63;
    int t = s*64 + cl;
    int n = n0 + r;
    float ai  = sP[0][r][cl] + sP[1][r][cl];
    float ao  = sP[2][r][cl] + sP[3][r][cl];
    float au  = sP[4][r][cl] + sP[5][r][cl];
    float af0 = sP[6][r][cl] + sP[7][r][cl];
    float af1 = sP[8][r][cl] + sP[9][r][cl];
    float c0 = cmat[(size_t)(offPrev+2*n)*256 + t];
    float c1 = cmat[(size_t)(offPrev+2*n+1)*256 + t];
    float i_ = sigmf(ai + b_iouh[t]);
    float o_ = sigmf(ao + b_iouh[256+t]);
    float u_ = tanhfast(au + b_iouh[512+t]);
    float bf = b_fh[t];
    float c = i_*u_ + sigmf(af0+bf)*c0 + sigmf(af1+bf)*c1;
    float h = o_*tanhfast(c);
    cmat[(size_t)(offCur+n)*256 + t] = c;
    hmat[(size_t)(offCur+n)*256 + t] = h;
  }
}

// ---------------------------------------------------------------------------
// Mid: proj rows (0..127), colsums (128,129), matT transposes (130..385),
// hp (php slice 0) for the 512 init rows of C/D (386..449).
// ---------------------------------------------------------------------------
__global__ void __launch_bounds__(256) k_mid(
    const float* __restrict__ W_attnh, const float* __restrict__ b_attnh,
    const float* __restrict__ matA, const float* __restrict__ matB,
    float* __restrict__ projA, float* __restrict__ projB,
    float* __restrict__ colA, float* __restrict__ colB,
    float* __restrict__ matTA, float* __restrict__ matTB,
    float* __restrict__ php)
{
  int b = blockIdx.x, tid = threadIdx.x;
  if (b < 128){
    int p = b>>6, ch = b&63, m0 = ch*8, mc = min(8, 511-m0);
    const float* mat = p ? matB : matA;
    float* proj = p ? projB : projA;
    __shared__ __align__(16) float ms[256*8];   // ms[e*8+rr]
    for (int j = tid; j < mc*256; j += 256){
      int rr = j>>8, e = j&255;
      ms[e*8+rr] = mat[(size_t)(m0+rr)*256 + e];
    }
    for (int j = tid + mc*256; j < 8*256; j += 256){
      int rr = j>>8, e = j&255; ms[e*8+rr] = 0.f;
    }
    __syncthreads();
    int t = tid;
    const float4* w2 = (const float4*)(W_attnh + (size_t)t*512 + 256);
    float acc[8] = {0,0,0,0,0,0,0,0};
    #pragma unroll 2
    for (int k = 0; k < 64; ++k){
      float4 w = w2[k];
      const float* base = ms + k*32;
      #pragma unroll
      for (int rr = 0; rr < 8; ++rr)
        acc[rr] += w.x*base[rr] + w.y*base[8+rr] + w.z*base[16+rr] + w.w*base[24+rr];
    }
    float ba = b_attnh[t];
    for (int rr = 0; rr < mc; ++rr) proj[(size_t)(m0+rr)*256 + t] = acc[rr] + ba;
  } else if (b < 130){
    int p = b - 128;
    const float* mat = p ? matB : matA;
    float* col = p ? colB : colA;
    float s = 0.f;
    #pragma unroll 8
    for (int m = 0; m < 511; ++m) s += mat[(size_t)m*256 + tid];
    col[tid] = s;
  } else if (b < 386){
    int idx = b - 130;
    int p = idx>>7, rem = idx&127, jt = rem>>4, mt = rem&15;
    const float* mat = p ? matB : matA;
    float* matT = p ? matTB : matTA;
    __shared__ float tile[32][33];
    int c = tid&31, r0 = tid>>5;
    int m0 = mt*32, j0 = jt*32;
    #pragma unroll
    for (int k = 0; k < 4; ++k){
      int m = m0 + r0 + 8*k;
      tile[r0+8*k][c] = (m < 511) ? mat[(size_t)m*256 + j0 + c] : 0.f;
    }
    __syncthreads();
    #pragma unroll
    for (int k = 0; k < 4; ++k){
      int jj = r0 + 8*k;
      matT[(size_t)(j0+jj)*MT + m0 + c] = tile[c][jj];
    }
  } else {
    int idx = b - 386;           // 64 blocks: p (C/D) x 32 chunks of 8 rows
    int p = idx>>5, ch = idx&31, r0 = ch*8;
    const float* hsrc = p ? matA : matB;   // C<-B, D<-A
    __shared__ __align__(16) float ms[256*8];
    for (int j = tid; j < 8*256; j += 256){
      int rr = j>>8, e = j&255;
      ms[e*8+rr] = hsrc[(size_t)(r0+rr)*256 + e];
    }
    __syncthreads();
    int t = tid;
    const float4* w1 = (const float4*)(W_attnh + (size_t)t*512);
    float acc[8] = {0,0,0,0,0,0,0,0};
    #pragma unroll 2
    for (int k = 0; k < 64; ++k){
      float4 w = w1[k];
      const float* base = ms + k*32;
      #pragma unroll
      for (int rr = 0; rr < 8; ++rr)
        acc[rr] += w.x*base[rr] + w.y*base[8+rr] + w.z*base[16+rr] + w.w*base[24+rr];
    }
    #pragma unroll
    for (int rr = 0; rr < 8; ++rr)
      php[(((size_t)p*511 + r0+rr)*4 + 0)*256 + t] = acc[rr];
  }
}

// ---------------------------------------------------------------------------
// Tiled scores: block = (pass, G-row group, m-chunk of 128). hp = sum of S
// php slices per row. Writes unnormalized wsumP + esumP.
// ---------------------------------------------------------------------------
template<int G>
__global__ void __launch_bounds__(256) k_scores_t(
    const float* __restrict__ php,
    const float* __restrict__ projA, const float* __restrict__ projB,
    const float* __restrict__ matTA, const float* __restrict__ matTB,
    const float* __restrict__ Wa, int Nc, int rowOff, int S,
    float* __restrict__ wsumP, float* __restrict__ esumP)
{
  int b = blockIdx.x, tid = threadIdx.x;
  int groups = Nc / G;
  int per = groups * 4;
  int p = b / per; int rem = b - p*per; int g = rem >> 2, ch = rem & 3;
  int row0 = rowOff + g*G;
  const float* proj = p ? projB : projA;
  const float* matT = p ? matTB : matTA;

  __shared__ __align__(16) float shp[G*256];
  __shared__ __align__(16) float swa[256];
  __shared__ __align__(16) float spart[G*256];
  __shared__ __align__(16) float se[G*128];

  for (int j = tid; j < G*256; j += 256){
    int row = row0 + (j>>8), jj = j&255;
    const float* base = php + (((size_t)p*511 + row)*4)*256 + jj;
    float v = base[0];
    if (S == 4) v += base[256] + base[512] + base[768];
    shp[j] = v;
  }
  swa[tid] = Wa[tid];
  __syncthreads();

  int ml = tid & 127, dh = tid >> 7;
  int m = ch*128 + ml;
  float part[G];
  #pragma unroll
  for (int r = 0; r < G; ++r) part[r] = 0.f;
  if (m < 511){
    const float4* pr  = (const float4*)(proj + (size_t)m*256 + dh*128);
    const float4* wa4 = (const float4*)(swa + dh*128);
    #pragma unroll 4
    for (int k = 0; k < 32; ++k){
      float4 pv = pr[k], wv = wa4[k];
      int dbase = dh*128 + k*4;
      #pragma unroll
      for (int r = 0; r < G; ++r){
        const float* hr = shp + r*256 + dbase;
        part[r] += wv.x*tanhfast(hr[0]+pv.x) + wv.y*tanhfast(hr[1]+pv.y)
                 + wv.z*tanhfast(hr[2]+pv.z) + wv.w*tanhfast(hr[3]+pv.w);
      }
    }
  }
  #pragma unroll
  for (int r = 0; r < G; ++r) spart[r*256 + tid] = part[r];
  __syncthreads();
  if (tid < 128){
    #pragma unroll
    for (int r = 0; r < G; ++r){
      float s = spart[r*256 + ml] + spart[r*256 + 128 + ml];
      se[r*128 + ml] = (ch*128 + ml < 511) ? __expf(s) : 0.f;
    }
  }
  __syncthreads();
  {
    const float4* mt = (const float4*)(matT + (size_t)tid*MT + ch*128);
    float acc[G];
    #pragma unroll
    for (int r = 0; r < G; ++r) acc[r] = 0.f;
    #pragma unroll 4
    for (int k = 0; k < 32; ++k){
      float4 mv = mt[k];
      #pragma unroll
      for (int r = 0; r < G; ++r){
        float4 ev = ((const float4*)(se + r*128))[k];
        acc[r] += mv.x*ev.x + mv.y*ev.y + mv.z*ev.z + mv.w*ev.w;
      }
    }
    #pragma unroll
    for (int r = 0; r < G; ++r)
      wsumP[(((size_t)p*511 + row0 + r)*4 + ch)*256 + tid] = acc[r];
  }
  if (tid < G){
    float s = 0.f;
    const float* sr = se + tid*128;
    for (int k = 0; k < 128; ++k) s += sr[k];
    esumP[((size_t)p*511 + row0 + tid)*4 + ch] = s;
  }
}

// ---------------------------------------------------------------------------
// CD spine, column-split S=4, row-batched R. 512 threads.
// Phase1: attend-finish children (full width). Phase2: gate dots (own cols).
// Phase3: c,h finalize (own cols). Phase4: hp partial slice -> php.
// ---------------------------------------------------------------------------
template<int R>
__global__ void __launch_bounds__(512) k_cd1(
    const unsigned short* __restrict__ W16, const float* __restrict__ b_iouh,
    const float* __restrict__ b_fh,
    int Nc, int offPrev, int offCur,
    const float* __restrict__ colA, const float* __restrict__ colB,
    const float* __restrict__ wsumP, const float* __restrict__ esumP,
    const float* __restrict__ childHC, const float* __restrict__ childHD,
    const float* __restrict__ childCC, const float* __restrict__ childCD_,
    float* __restrict__ cmatC, float* __restrict__ cmatD,
    float* __restrict__ hstageC, float* __restrict__ hstageD,
    float* __restrict__ php)
{
  int bid = blockIdx.x, tid = threadIdx.x;
  int s = bid & 3, g2 = bid >> 2;
  int groups = Nc / R;
  int p = (g2 >= groups) ? 1 : 0;
  int n0 = (g2 - p*groups) * R;
  const float* colv   = p ? colB : colA;
  const float* childH = p ? childHD : childHC;
  const float* childC = p ? childCD_ : childCC;
  float* cmat   = p ? cmatD : cmatC;
  float* hstage = p ? hstageD : hstageC;

  __shared__ __align__(16) float hs0[R][256], hs1[R][256], hss[R][256];
  __shared__ float sP[10][R][64];
  __shared__ __align__(16) float sh[R][64];
  __shared__ float sHP[2][256];

  // Phase 1: attend-finish both children of each of the R rows (full width)
  for (int it = tid; it < R*2*256; it += 512){
    int j = it & 255, ch = (it>>8)&1, r = it>>9;
    int rc = offPrev + 2*(n0+r) + ch;
    const float* wp = wsumP + (((size_t)p*511 + rc)*4)*256;
    const float* ep = esumP + ((size_t)p*511 + rc)*4;
    float w = wp[j] + wp[256+j] + wp[512+j] + wp[768+j];
    float esum = ep[0]+ep[1]+ep[2]+ep[3];
    float hatt = colv[j] - w*rcpf(esum) + childH[(size_t)rc*256 + j];
    if (ch) hs1[r][j] = hatt; else hs0[r][j] = hatt;
  }
  __syncthreads();
  for (int it = tid; it < R*256; it += 512){
    int j = it & 255, r = it>>8;
    hss[r][j] = hs0[r][j] + hs1[r][j];
  }
  __syncthreads();

  // Phase 2: gate dots for own 64 columns
  {
    int role = tid >> 6, cl = tid & 63;
    int gate = role & 3, dh = role >> 2;
    int col = s*64 + cl;
    if (gate < 3){
      const unsigned short* wrow = W16 + (size_t)(col + gate*256)*256;
      const uint4* w4 = (const uint4*)(wrow + dh*128);
      float acc[R];
      #pragma unroll
      for (int r = 0; r < R; ++r) acc[r] = 0.f;
      #pragma unroll 4
      for (int k = 0; k < 16; ++k){
        uint4 w = w4[k];
        #pragma unroll
        for (int r = 0; r < R; ++r)
          acc[r] += dot8b(w, (const float4*)(&hss[r][dh*128 + k*8]));
      }
      #pragma unroll
      for (int r = 0; r < R; ++r) sP[gate*2+dh][r][cl] = acc[r];
    } else {
      const uint4* w4 = (const uint4*)(W16 + B16_FH + (size_t)col*256 + dh*128);
      float a0[R], a1[R];
      #pragma unroll
      for (int r = 0; r < R; ++r){ a0[r] = 0.f; a1[r] = 0.f; }
      #pragma unroll 4
      for (int k = 0; k < 16; ++k){
        uint4 w = w4[k];
        #pragma unroll
        for (int r = 0; r < R; ++r){
          a0[r] += dot8b(w, (const float4*)(&hs0[r][dh*128 + k*8]));
          a1[r] += dot8b(w, (const float4*)(&hs1[r][dh*128 + k*8]));
        }
      }
      #pragma unroll
      for (int r = 0; r < R; ++r){ sP[6+dh][r][cl] = a0[r]; sP[8+dh][r][cl] = a1[r]; }
    }
  }
  __syncthreads();

  // Phase 3: finalize c,h for own columns
  if (tid < 64*R){
    int r = tid >> 6, cl = tid & 63;
    int t = s*64 + cl;
    int n = n0 + r;
    float ai  = sP[0][r][cl] + sP[1][r][cl];
    float ao  = sP[2][r][cl] + sP[3][r][cl];
    float au  = sP[4][r][cl] + sP[5][r][cl];
    float af0 = sP[6][r][cl] + sP[7][r][cl];
    float af1 = sP[8][r][cl] + sP[9][r][cl];
    float c0 = childC[(size_t)(offPrev+2*n)*256 + t];
    float c1 = childC[(size_t)(offPrev+2*n+1)*256 + t];
    float i_ = sigmf(ai + b_iouh[t]);
    float o_ = sigmf(ao + b_iouh[256+t]);
    float u_ = tanhfast(au + b_iouh[512+t]);
    float bf = b_fh[t];
    float c = i_*u_ + sigmf(af0+bf)*c0 + sigmf(af1+bf)*c1;
    float h = o_*tanhfast(c);
    cmat[(size_t)(offCur+n)*256 + t] = c;
    hstage[(size_t)(offCur+n)*256 + t] = h;
    sh[r][cl] = h;
  }
  __syncthreads();

  // Phase 4: hp partial over own e-slice -> php[p][row][s][:]
  {
    int j = tid & 255, eh = tid >> 8;
    const uint4* w1 = (const uint4*)(W16 + B16_W1 + (size_t)j*256 + s*64 + eh*32);
    uint4 wv[4];
    #pragma unroll
    for (int k = 0; k < 4; ++k) wv[k] = w1[k];
    float aacc[R];
    #pragma unroll
    for (int r = 0; r < R; ++r){
      float a = 0.f;
      #pragma unroll
      for (int k = 0; k < 4; ++k)
        a += dot8b(wv[k], (const float4*)(&sh[r][eh*32 + k*8]));
      aacc[r] = a;
    }
    #pragma unroll
    for (int r = 0; r < R; ++r){
      sHP[eh][j] = aacc[r];
      __syncthreads();
      if (tid < 256){
        int row = offCur + n0 + r;
        php[(((size_t)p*511 + row)*4 + s)*256 + tid] = sHP[0][tid] + sHP[1][tid];
      }
      __syncthreads();
    }
  }
}

// ---------------------------------------------------------------------------
// Head: finish row 510 of C and D, then MLP + log_softmax. 1 block x 256.
// ---------------------------------------------------------------------------
__global__ void __launch_bounds__(256) k_head(
    const float* __restrict__ W_wh, const float* __restrict__ b_wh,
    const float* __restrict__ W_wp, const float* __restrict__ b_wp,
    const float* __restrict__ matA, const float* __restrict__ matB,
    const float* __restrict__ colA, const float* __restrict__ colB,
    const float* __restrict__ wsumP, const float* __restrict__ esumP,
    const float* __restrict__ hstageC, const float* __restrict__ hstageD,
    float* __restrict__ out)
{
  __shared__ __align__(16) float v[512];
  __shared__ float og[128], lg[5];
  int t = threadIdx.x;
  {
    const float* wpC = wsumP + (((size_t)0*511 + 510)*4)*256;
    const float* epC = esumP + ((size_t)0*511 + 510)*4;
    float wC = wpC[t] + wpC[256+t] + wpC[512+t] + wpC[768+t];
    float eC = epC[0]+epC[1]+epC[2]+epC[3];
    float hCf = colA[t] - wC*rcpf(eC) + hstageC[(size_t)510*256 + t];
    const float* wpD = wsumP + (((size_t)1*511 + 510)*4)*256;
    const float* epD = esumP + ((size_t)1*511 + 510)*4;
    float wD = wpD[t] + wpD[256+t] + wpD[512+t] + wpD[768+t];
    float eD = epD[0]+epD[1]+epD[2]+epD[3];
    float hDf = colB[t] - wD*rcpf(eD) + hstageD[(size_t)510*256 + t];
    float lh = tanhfast(matA[(size_t)510*256 + t] + hDf);
    float rh = tanhfast(hCf + matB[(size_t)510*256 + t]);
    v[t] = lh*rh;
    v[256+t] = fabsf(lh - rh);
  }
  __syncthreads();
  if (t < 128){
    const float4* w = (const float4*)(W_wh + (size_t)t*512);
    const float4* vv = (const float4*)v;
    float a = b_wh[t];
    #pragma unroll 4
    for (int k = 0; k < 128; ++k){
      float4 wv = w[k], x = vv[k];
      a += wv.x*x.x + wv.y*x.y + wv.z*x.z + wv.w*x.w;
    }
    og[t] = sigmf(a);
  }
  __syncthreads();
  if (t < 5){
    const float* wp = W_wp + (size_t)t*128;
    float a = b_wp[t];
    for (int j = 0; j < 128; ++j) a += og[j]*wp[j];
    lg[t] = a;
  }
  __syncthreads();
  if (t == 0){
    float M = -1e30f;
    for (int c = 0; c < 5; ++c) M = fmaxf(M, lg[c]);
    float S = 0.f;
    for (int c = 0; c < 5; ++c) S += __expf(lg[c] - M);
    float L = logf(S);
    for (int c = 0; c < 5; ++c) out[c] = lg[c] - M - L;
  }
}

extern "C" void kernel_launch(void* const* d_in, const int* in_sizes, int n_in,
                              void* d_out, int out_size, void* d_ws, size_t ws_size,
                              hipStream_t stream)
{
  const int*   l_idx   = (const int*)  d_in[0];
  const int*   r_idx   = (const int*)  d_in[1];
  const float* emb     = (const float*)d_in[2];
  const float* W_ioux  = (const float*)d_in[3];
  const float* b_ioux  = (const float*)d_in[4];
  const float* W_iouh  = (const float*)d_in[5];
  const float* b_iouh  = (const float*)d_in[6];
  // d_in[7]=W_fx, d_in[8]=b_fx unused by the forward
  const float* W_fh    = (const float*)d_in[9];
  const float* b_fh    = (const float*)d_in[10];
  const float* Wa      = (const float*)d_in[11];
  const float* W_attnh = (const float*)d_in[12];
  const float* b_attnh = (const float*)d_in[13];
  const float* W_wh    = (const float*)d_in[14];
  const float* b_wh    = (const float*)d_in[15];
  const float* W_wp    = (const float*)d_in[16];
  const float* b_wp    = (const float*)d_in[17];

  float* ws = (float*)d_ws;
  float* cmatA   = ws;               float* cmatB   = cmatA + RC;
  float* cmatC   = cmatB + RC;       float* cmatD   = cmatC + RC;
  float* matA    = cmatD + RC;       float* matB    = matA + RC;
  float* hstageC = matB + RC;        float* hstageD = hstageC + RC;
  float* projA   = hstageD + RC;     float* projB   = projA + RC;
  float* matTA   = projB + RC;       float* matTB   = matTA + 256*MT;
  float* colA    = matTB + 256*MT;   float* colB    = colA + 256;
  float* wsumP   = colB + 256;            // 2*511*4*256
  float* esumP   = wsumP + 2*511*4*256;   // 2*511*4
  float* php     = esumP + 2*511*4;       // 2*511*4*256
  unsigned short* W16 = (unsigned short*)(php + 2*511*4*256);  // 327,680 ushorts
  // total ~15.4 MB (ws is ~268 MB)

  static const int offs[9] = {0, 256, 384, 448, 480, 496, 504, 508, 510};

  k_pack<<<128, 256, 0, stream>>>(W_iouh, W_fh, W_attnh, (unsigned*)W16);
  k_init<<<256, 768, 0, stream>>>(l_idx, r_idx, emb, W_ioux, b_ioux, b_iouh,
                                  cmatA, matA, cmatB, matB);
  for (int i = 1; i <= 8; ++i){
    int Nc = 256 >> i;
    int oP = offs[i-1], oC = offs[i];
    if (Nc >= 128)
      k_levelAB<4><<<(2*Nc/4)*4, 512, 0, stream>>>(W16, b_iouh, b_fh, Nc, oP, oC,
                                                   cmatA, matA, cmatB, matB);
    else if (Nc >= 64)
      k_levelAB<2><<<(2*Nc/2)*4, 512, 0, stream>>>(W16, b_iouh, b_fh, Nc, oP, oC,
                                                   cmatA, matA, cmatB, matB);
    else
      k_levelAB<1><<<(2*Nc)*4, 512, 0, stream>>>(W16, b_iouh, b_fh, Nc, oP, oC,
                                                 cmatA, matA, cmatB, matB);
  }
  k_mid<<<450, 256, 0, stream>>>(W_attnh, b_attnh, matA, matB,
                                 projA, projB, colA, colB, matTA, matTB, php);
  // scores for the 512 "level-0" rows of C and D (G=4, S=1)
  k_scores_t<4><<<2*(256/4)*4, 256, 0, stream>>>(php, projA, projB,
                                                 matTA, matTB, Wa, 256, 0, 1,
                                                 wsumP, esumP);
  for (int i = 1; i <= 8; ++i){
    int Nc = 256 >> i;
    int oP = offs[i-1], oC = offs[i];
    const float* childHC = (i == 1) ? matB  : hstageC;  // C's h0 = pass-B rows
    const float* childHD = (i == 1) ? matA  : hstageD;
    const float* childCC = (i == 1) ? cmatB : cmatC;
    const float* childCD = (i == 1) ? cmatA : cmatD;
    if (Nc >= 128)
      k_cd1<4><<<(2*Nc/4)*4, 512, 0, stream>>>(W16, b_iouh, b_fh, Nc, oP, oC,
                                               colA, colB, wsumP, esumP,
                                               childHC, childHD, childCC, childCD,
                                               cmatC, cmatD, hstageC, hstageD, php);
    else if (Nc >= 64)
      k_cd1<2><<<(2*Nc/2)*4, 512, 0, stream>>>(W16, b_iouh, b_fh, Nc, oP, oC,
                                               colA, colB, wsumP, esumP,
                                               childHC, childHD, childCC, childCD,
                                               cmatC, cmatD, hstageC, hstageD, php);
    else
      k_cd1<1><<<(2*Nc)*4, 512, 0, stream>>>(W16, b_iouh, b_fh, Nc, oP, oC,
                                             colA, colB, wsumP, esumP,
                                             childHC, childHD, childCC, childCD,
                                             cmatC, cmatD, hstageC, hstageD, php);
    if (Nc >= 4)
      k_scores_t<4><<<2*(Nc/4)*4, 256, 0, stream>>>(php, projA, projB,
                                                    matTA, matTB, Wa, Nc, offs[i], 4,
                                                    wsumP, esumP);
    else if (Nc == 2)
      k_scores_t<2><<<2*(Nc/2)*4, 256, 0, stream>>>(php, projA, projB,
                                                    matTA, matTB, Wa, Nc, offs[i], 4,
                                                    wsumP, esumP);
    else
      k_scores_t<1><<<2*Nc*4, 256, 0, stream>>>(php, projA, projB,
                                                matTA, matTB, Wa, Nc, offs[i], 4,
                                                wsumP, esumP);
  }
  k_head<<<1, 256, 0, stream>>>(W_wh, b_wh, W_wp, b_wp, matA, matB,
                                colA, colB, wsumP, esumP, hstageC, hstageD,
                                (float*)d_out);
}